// Round 9
// baseline (100.534 us; speedup 1.0000x reference)
//
#include <hip/hip_runtime.h>

#define HW    (128*128)
#define DHW   (128*128*128)
#define NTOT  (4*DHW)
#define NBLK  (16*128*4)   // reduce_all block count = 8192

__device__ __forceinline__ float sigf(float x){ return 1.0f/(1.0f+__expf(-x)); }
__device__ __forceinline__ float4 ld4(const float* p){ return *(const float4*)p; }

// ws float layout: p_occ[NBLK], p_surf[NBLK], p_over[NBLK], p_trap[4]

// ---------------------------------------------------------------------------
// reduce_all: occupancy / surface / overhang in one pass over v.
// block (32,8) tile: y rows [y0..y0+7] of slice z. Below-plane rows
// y0-1..y0+8 (zero-padded OOB + zeroed edge words) staged in LDS via b128;
// all 9-point reads are LDS. Per-block partials to ws — NO global atomics
// (R7: 8192 same-address atomics serialized -> 418 us).
// ---------------------------------------------------------------------------
__global__ __launch_bounds__(256) void reduce_all_k(
    const float* __restrict__ v, float* __restrict__ p_occ,
    float* __restrict__ p_surf, float* __restrict__ p_over)
{
    __shared__ float rows[10][132];
    __shared__ float sm[3][4];

    const int tx = threadIdx.x, ty = threadIdx.y;
    const int tid = ty*32 + tx;
    const int y0 = blockIdx.x*8;
    const int y  = y0 + ty;
    const int z  = blockIdx.y;
    const int b  = blockIdx.z;
    const int x4 = tx*4;
    const size_t idx = (size_t)b*DHW + ((size_t)z*128 + y)*128 + x4;

    if (z >= 1) {
        const float* bp = v + (size_t)b*DHW + (size_t)(z-1)*HW;
        const float4 zero = make_float4(0,0,0,0);
        for (int i = tid; i < 320; i += 256) {
            int r = i >> 5, q = (i & 31)*4;
            int gy = y0 - 1 + r;
            float4 qv = ((unsigned)gy <= 127u) ? ld4(bp + (size_t)gy*128 + q) : zero;
            *(float4*)&rows[r][q] = qv;
        }
        if (tid < 20) rows[tid>>1][130 + (tid&1)] = 0.f;
    }
    __syncthreads();

    float4 val = ld4(v + idx);
    float occ = val.x + val.y + val.z + val.w;

    float wz = (z==0 || z==127) ? 2.f : 3.f;
    float wy = (y==0 || y==127) ? 2.f : 3.f;
    float wx0 = (x4==0)   ? 2.f : 3.f;
    float wx3 = (x4==124) ? 2.f : 3.f;
    float surf = wz*wy*(wx0*val.x + 3.f*val.y + 3.f*val.z + wx3*val.w);

    float over = 0.f;
    if (z >= 1) {
        float sx=0, sy=0, szz=0, sw=0;
        #pragma unroll
        for (int dy = 0; dy < 3; ++dy) {
            const float* R = rows[ty + dy];
            float4 q = *(const float4*)&R[x4];
            float ql = R[(tx==0)  ? 130 : x4-1];
            float qr = R[(tx==31) ? 131 : x4+4];
            sx  += ql  + q.x + q.y;
            sy  += q.x + q.y + q.z;
            szz += q.y + q.z + q.w;
            sw  += q.z + q.w + qr;
        }
        const float inv9 = 1.f/9.f;
        over = val.x*(1.f - sx*inv9) + val.y*(1.f - sy*inv9)
             + val.z*(1.f - szz*inv9) + val.w*(1.f - sw*inv9);
    }

    #pragma unroll
    for (int o = 32; o; o >>= 1) {
        occ  += __shfl_down(occ,  o, 64);
        surf += __shfl_down(surf, o, 64);
        over += __shfl_down(over, o, 64);
    }
    int lane = tid & 63, wid = tid >> 6;
    if (lane == 0) { sm[0][wid]=occ; sm[1][wid]=surf; sm[2][wid]=over; }
    __syncthreads();
    if (tid == 0) {
        int blin = (b*gridDim.y + blockIdx.y)*gridDim.x + blockIdx.x;
        p_occ [blin] = sm[0][0]+sm[0][1]+sm[0][2]+sm[0][3];
        p_surf[blin] = sm[1][0]+sm[1][1]+sm[1][2]+sm[1][3];
        p_over[blin] = sm[2][0]+sm[2][1]+sm[2][2]+sm[2][3];
    }
}

// ---------------------------------------------------------------------------
// Resin-trap box sim. Deviation from the background fixed point
// m_bg = a_lo*(1-v) is confined to Manhattan distance <= 10 from seed (5,5,5),
// i.e. cells [0,15]^3. Simulate exactly (iter 1 analytic + 9 Jacobi iters).
// 256 threads: thread (y,z) owns its full x-row [0..15] in REGISTERS
// (fully unrolled -> no scratch; x-neighbors free). LDS holds the ping-pong
// mask boxes [17][17][20] whose +faces carry the constant background value
// (pre-filled in both buffers); -faces are out-of-grid -> 0. All LDS traffic
// is explicit float4 (R8 scalar-b32 version ran ~20us; this is ~2x fewer
// LDS cycles). One barrier per iteration. grid = 4 batches.
// ---------------------------------------------------------------------------
__global__ __launch_bounds__(256) void trap_box_k(
    const float* __restrict__ v, float* __restrict__ p_trap)
{
    __shared__ float mbuf[2][17][17][20];
    __shared__ float nvL[16][16][20];
    __shared__ float red[4];

    const int b = blockIdx.x;
    const size_t gb = (size_t)b * DHW;
    const int tid = threadIdx.x;
    const int ty = tid & 15, tz = tid >> 4;
    const float a_lo = sigf(-10.0f), a_hi = sigf(10.0f);
    const float4 zero4 = make_float4(0,0,0,0);

    // own-row init: nv + analytic iteration-1 mask, rows kept in registers
    float m[16];
    {
        const float* rv = v + gb + ((size_t)tz*128 + ty)*128;
        int dzy = abs(tz-5) + abs(ty-5);
        #pragma unroll
        for (int q = 0; q < 4; ++q) {
            int x4 = 4*q;
            float4 a = ld4(rv + x4);
            float nv0=1.f-a.x, nv1=1.f-a.y, nv2=1.f-a.z, nv3=1.f-a.w;
            *(float4*)&nvL[tz][ty][x4] = make_float4(nv0,nv1,nv2,nv3);
            int d0 = dzy+abs(x4+0-5), d1 = dzy+abs(x4+1-5);
            int d2 = dzy+abs(x4+2-5), d3 = dzy+abs(x4+3-5);
            m[x4+0] = ((d0==0)?1.f:((d0==1)?a_hi:a_lo)) * nv0;
            m[x4+1] = ((d1==0)?1.f:((d1==1)?a_hi:a_lo)) * nv1;
            m[x4+2] = ((d2==0)?1.f:((d2==1)?a_hi:a_lo)) * nv2;
            m[x4+3] = ((d3==0)?1.f:((d3==1)?a_hi:a_lo)) * nv3;
            *(float4*)&mbuf[0][tz][ty][x4] = make_float4(m[x4+0],m[x4+1],m[x4+2],m[x4+3]);
        }
    }
    // background +faces into BOTH buffers (constant across iterations)
    {
        // 3 faces x 256 entries, one per thread per face
        #pragma unroll
        for (int f = 0; f < 3; ++f) {
            int a = tid >> 4, e = tid & 15;
            int zz, yy, xx;
            if (f == 0)      { zz = 16; yy = a;  xx = e;  }
            else if (f == 1) { zz = a;  yy = 16; xx = e;  }
            else             { zz = a;  yy = e;  xx = 16; }
            float bgv = a_lo * (1.f - v[gb + ((size_t)zz*128 + yy)*128 + xx]);
            mbuf[0][zz][yy][xx] = bgv;
            mbuf[1][zz][yy][xx] = bgv;
        }
    }
    __syncthreads();

    int cur = 0;
    for (int it = 0; it < 9; ++it) {
        const float* YM = &mbuf[cur][tz][ty-1][0];
        const float* YP = &mbuf[cur][tz][ty+1][0];   // ty+1 <= 16 (bg row)
        const float* ZM = &mbuf[cur][tz-1][ty][0];
        const float* ZP = &mbuf[cur][tz+1][ty][0];
        const float  xrE = mbuf[cur][tz][ty][16];     // bg, x=16
        float* W = &mbuf[cur^1][tz][ty][0];
        float nm[16];
        #pragma unroll
        for (int q = 0; q < 4; ++q) {
            int x4 = 4*q;
            float4 ym = (ty > 0) ? *(const float4*)&YM[x4] : zero4;
            float4 yp = *(const float4*)&YP[x4];
            float4 zm = (tz > 0) ? *(const float4*)&ZM[x4] : zero4;
            float4 zp = *(const float4*)&ZP[x4];
            float4 nv = *(const float4*)&nvL[tz][ty][x4];
            float xl = (q == 0) ? 0.f : m[x4-1];
            float xr = (q == 3) ? xrE : m[x4+4];
            float s0 = xl      + m[x4+1] + ym.x + yp.x + zm.x + zp.x;
            float s1 = m[x4+0] + m[x4+2] + ym.y + yp.y + zm.y + zp.y;
            float s2 = m[x4+1] + m[x4+3] + ym.z + yp.z + zm.z + zp.z;
            float s3 = m[x4+2] + xr      + ym.w + yp.w + zm.w + zp.w;
            nm[x4+0] = fmaxf(m[x4+0], sigf(20.f*s0 - 10.f)) * nv.x;
            nm[x4+1] = fmaxf(m[x4+1], sigf(20.f*s1 - 10.f)) * nv.y;
            nm[x4+2] = fmaxf(m[x4+2], sigf(20.f*s2 - 10.f)) * nv.z;
            nm[x4+3] = fmaxf(m[x4+3], sigf(20.f*s3 - 10.f)) * nv.w;
            *(float4*)&W[x4] = make_float4(nm[x4+0],nm[x4+1],nm[x4+2],nm[x4+3]);
        }
        #pragma unroll
        for (int x = 0; x < 16; ++x) m[x] = nm[x];   // Jacobi: after full sweep
        __syncthreads();
        cur ^= 1;
    }

    // delta vs background fixed point
    float d = 0.f;
    #pragma unroll
    for (int x = 0; x < 16; ++x) d += m[x] - a_lo * nvL[tz][ty][x];
    #pragma unroll
    for (int o = 32; o; o >>= 1) d += __shfl_down(d, o, 64);
    int lane = tid & 63, wid = tid >> 6;
    if (lane == 0) red[wid] = d;
    __syncthreads();
    if (tid == 0) p_trap[b] = red[0] + red[1] + red[2] + red[3];
}

// ---------------------------------------------------------------------------
// finalize: sum partials (f64), combine with trap deltas.
// trap_sum = a_lo*(N - sum(v)) + sum(box deltas)
// ---------------------------------------------------------------------------
__global__ __launch_bounds__(1024) void finalize_k(
    const float* __restrict__ p_occ, const float* __restrict__ p_surf,
    const float* __restrict__ p_over, const float* __restrict__ p_trap,
    float* __restrict__ out)
{
    double occ=0, surf=0, over=0;
    for (int i = threadIdx.x; i < NBLK; i += 1024) {
        occ += p_occ[i]; surf += p_surf[i]; over += p_over[i];
    }
    __shared__ double sm[3][16];
    #pragma unroll
    for (int o = 32; o; o >>= 1) {
        occ  += __shfl_down(occ,  o, 64);
        surf += __shfl_down(surf, o, 64);
        over += __shfl_down(over, o, 64);
    }
    int lane = threadIdx.x & 63, wid = threadIdx.x >> 6;
    if (lane == 0) { sm[0][wid]=occ; sm[1][wid]=surf; sm[2][wid]=over; }
    __syncthreads();
    if (threadIdx.x == 0) {
        double so=0, ss=0, sv=0;
        for (int w = 0; w < 16; ++w) { so+=sm[0][w]; ss+=sm[1][w]; sv+=sm[2][w]; }
        double dS = (double)p_trap[0] + p_trap[1] + p_trap[2] + p_trap[3];
        double a_lo = 1.0 / (1.0 + exp(10.0));
        double N = (double)NTOT;
        double trap_sum = a_lo * (N - so) + dS;
        double occupancy = so / N;
        double occ_pen = 10.0 * (occupancy - 0.5) * (occupancy - 0.5);
        out[0] = (float)(sv / N);
        out[1] = (float)(ss / 27.0 / N - 100.0 * trap_sum / N - occ_pen);
    }
}

extern "C" void kernel_launch(void* const* d_in, const int* in_sizes, int n_in,
                              void* d_out, int out_size, void* d_ws, size_t ws_size,
                              hipStream_t stream)
{
    const float* v = (const float*)d_in[0];
    float* out = (float*)d_out;
    float* ws = (float*)d_ws;

    float* p_occ  = ws;
    float* p_surf = p_occ  + NBLK;
    float* p_over = p_surf + NBLK;
    float* p_trap = p_over + NBLK;   // 4 floats

    // reduce first (kicks off the HBM-heavy stream immediately); trap's tiny
    // v reads then hit L2/L3.
    reduce_all_k<<<dim3(16,128,4), dim3(32,8,1), 0, stream>>>(v, p_occ, p_surf, p_over);
    trap_box_k<<<4, 256, 0, stream>>>(v, p_trap);
    finalize_k<<<1, 1024, 0, stream>>>(p_occ, p_surf, p_over, p_trap, out);
}

// Round 10
// 89.227 us; speedup vs baseline: 1.1267x; 1.1267x over previous
//
#include <hip/hip_runtime.h>

#define HW    (128*128)
#define DHW   (128*128*128)
#define NTOT  (4*DHW)
#define NBLK  8192         // reduce blocks (16 y-tiles * 128 z * 4 batches)

__device__ __forceinline__ float sigf(float x){ return 1.0f/(1.0f+__expf(-x)); }
__device__ __forceinline__ float4 ld4(const float* p){ return *(const float4*)p; }

// ws float layout: p_occ[NBLK], p_surf[NBLK], p_over[NBLK], p_trap[4]

// ---------------------------------------------------------------------------
// mega_k: heterogeneous grid of 4+NBLK blocks.
//   blocks 0..3      : resin-trap 16^3 box sim (one per batch) — LDS/VALU-bound,
//                      runs concurrently with (hidden under) the reduce blocks.
//   blocks 4..NBLK+3 : occupancy/surface/overhang reduction — HBM-bound.
// Shared LDS pool is overlaid: trap uses 17*17*20 floats (single mask buffer,
// Jacobi via read-phase barrier / write-phase barrier); reduce uses 10*132.
// Trap blocks come FIRST in the grid so they are dispatched immediately.
// ---------------------------------------------------------------------------
__global__ __launch_bounds__(256, 4) void mega_k(
    const float* __restrict__ v, float* __restrict__ p_occ,
    float* __restrict__ p_surf, float* __restrict__ p_over,
    float* __restrict__ p_trap)
{
    __shared__ float4 smem4[1445];          // 5780 floats = 23.1 KB, 16B aligned
    __shared__ float sred[16];
    float* smem = (float*)smem4;

    const int bid = blockIdx.x;
    const int tid = threadIdx.x;

    if (bid < 4) {
        // ================= trap box path =================
        // Background fixed point m_bg = a_lo*(1-v); deviation confined to
        // Manhattan d<=10 from seed (5,5,5) -> box [0,15]^3. Iter 1 analytic,
        // then 9 Jacobi iterations. Single LDS buffer mbuf[17][17][20]
        // (stride 20 -> conflict-free b128); +faces z=16,y=16 hold constant
        // background; x=16 neighbor hoisted to register; -faces are 0.
        const int b = bid;
        const size_t gb = (size_t)b * DHW;
        const int ty = tid & 15, tz = tid >> 4;
        const float a_lo = sigf(-10.0f), a_hi = sigf(10.0f);
        const float4 zero4 = make_float4(0,0,0,0);
        #define M(zz,yy) (smem + (((zz)*17 + (yy))*20))

        float m[16], nv[16];
        {
            const float* rv = v + gb + ((size_t)tz*128 + ty)*128;
            int dzy = abs(tz-5) + abs(ty-5);
            #pragma unroll
            for (int q = 0; q < 4; ++q) {
                int x4 = 4*q;
                float4 a = ld4(rv + x4);
                nv[x4+0]=1.f-a.x; nv[x4+1]=1.f-a.y; nv[x4+2]=1.f-a.z; nv[x4+3]=1.f-a.w;
                int d0=dzy+abs(x4+0-5), d1=dzy+abs(x4+1-5);
                int d2=dzy+abs(x4+2-5), d3=dzy+abs(x4+3-5);
                m[x4+0] = ((d0==0)?1.f:((d0==1)?a_hi:a_lo)) * nv[x4+0];
                m[x4+1] = ((d1==0)?1.f:((d1==1)?a_hi:a_lo)) * nv[x4+1];
                m[x4+2] = ((d2==0)?1.f:((d2==1)?a_hi:a_lo)) * nv[x4+2];
                m[x4+3] = ((d3==0)?1.f:((d3==1)?a_hi:a_lo)) * nv[x4+3];
                *(float4*)(M(tz,ty) + x4) = make_float4(m[x4+0],m[x4+1],m[x4+2],m[x4+3]);
            }
        }
        const float xrE = a_lo * (1.f - v[gb + ((size_t)tz*128 + ty)*128 + 16]);
        {   // background faces z=16 (ZP of tz=15) and y=16 (YP of ty=15)
            int a = tid >> 4, e = tid & 15;
            M(16,a)[e] = a_lo * (1.f - v[gb + ((size_t)16*128 + a)*128 + e]);
            M(a,16)[e] = a_lo * (1.f - v[gb + ((size_t)a*128 + 16)*128 + e]);
        }
        __syncthreads();

        for (int it = 0; it < 9; ++it) {
            const float* YM = M(tz,ty-1);
            const float* YP = M(tz,ty+1);    // ty=15 -> bg row (never rewritten)
            const float* ZM = M(tz-1,ty);
            const float* ZP = M(tz+1,ty);    // tz=15 -> bg plane
            float nm[16];
            #pragma unroll
            for (int q = 0; q < 4; ++q) {
                int x4 = 4*q;
                float4 ym = (ty > 0) ? *(const float4*)(YM + x4) : zero4;
                float4 yp = *(const float4*)(YP + x4);
                float4 zm = (tz > 0) ? *(const float4*)(ZM + x4) : zero4;
                float4 zp = *(const float4*)(ZP + x4);
                float xl = (q == 0) ? 0.f : m[x4-1];
                float xr = (q == 3) ? xrE : m[x4+4];
                float s0 = xl      + m[x4+1] + ym.x + yp.x + zm.x + zp.x;
                float s1 = m[x4+0] + m[x4+2] + ym.y + yp.y + zm.y + zp.y;
                float s2 = m[x4+1] + m[x4+3] + ym.z + yp.z + zm.z + zp.z;
                float s3 = m[x4+2] + xr      + ym.w + yp.w + zm.w + zp.w;
                nm[x4+0] = fmaxf(m[x4+0], sigf(20.f*s0 - 10.f)) * nv[x4+0];
                nm[x4+1] = fmaxf(m[x4+1], sigf(20.f*s1 - 10.f)) * nv[x4+1];
                nm[x4+2] = fmaxf(m[x4+2], sigf(20.f*s2 - 10.f)) * nv[x4+2];
                nm[x4+3] = fmaxf(m[x4+3], sigf(20.f*s3 - 10.f)) * nv[x4+3];
            }
            __syncthreads();   // ALL reads of mbuf done (Jacobi)
            float* W = M(tz,ty);
            #pragma unroll
            for (int q = 0; q < 4; ++q) {
                int x4 = 4*q;
                *(float4*)(W + x4) = make_float4(nm[x4+0],nm[x4+1],nm[x4+2],nm[x4+3]);
                m[x4+0]=nm[x4+0]; m[x4+1]=nm[x4+1]; m[x4+2]=nm[x4+2]; m[x4+3]=nm[x4+3];
            }
            __syncthreads();
        }

        float d = 0.f;
        #pragma unroll
        for (int x = 0; x < 16; ++x) d += m[x] - a_lo * nv[x];
        #pragma unroll
        for (int o = 32; o; o >>= 1) d += __shfl_down(d, o, 64);
        int lane = tid & 63, wid = tid >> 6;
        if (lane == 0) sred[wid] = d;
        __syncthreads();
        if (tid == 0) p_trap[b] = sred[0] + sred[1] + sred[2] + sred[3];
        #undef M
    } else {
        // ================= reduce path =================
        const int rid = bid - 4;                 // 0..8191
        const int b   = rid >> 11;               // batch
        const int rem = rid & 2047;
        const int z   = rem >> 4;
        const int y0  = (rem & 15) * 8;
        const int tx  = tid & 31, ty = tid >> 5;
        const int y   = y0 + ty;
        const int x4  = tx * 4;
        const size_t idx = (size_t)b*DHW + ((size_t)z*128 + y)*128 + x4;
        #define ROWS(r) (smem + (r)*132)

        if (z >= 1) {
            const float* bp = v + (size_t)b*DHW + (size_t)(z-1)*HW;
            const float4 zero = make_float4(0,0,0,0);
            for (int i = tid; i < 320; i += 256) {
                int r = i >> 5, q = (i & 31)*4;
                int gy = y0 - 1 + r;
                float4 qv = ((unsigned)gy <= 127u) ? ld4(bp + (size_t)gy*128 + q) : zero;
                *(float4*)(ROWS(r) + q) = qv;
            }
            if (tid < 20) ROWS(tid>>1)[130 + (tid&1)] = 0.f;
        }
        __syncthreads();

        float4 val = ld4(v + idx);
        float occ = val.x + val.y + val.z + val.w;

        float wz = (z==0 || z==127) ? 2.f : 3.f;
        float wy = (y==0 || y==127) ? 2.f : 3.f;
        float wx0 = (x4==0)   ? 2.f : 3.f;
        float wx3 = (x4==124) ? 2.f : 3.f;
        float surf = wz*wy*(wx0*val.x + 3.f*val.y + 3.f*val.z + wx3*val.w);

        float over = 0.f;
        if (z >= 1) {
            float sx=0, sy=0, szz=0, sw=0;
            #pragma unroll
            for (int dy = 0; dy < 3; ++dy) {
                const float* R = ROWS(ty + dy);
                float4 q = *(const float4*)(R + x4);
                float ql = R[(tx==0)  ? 130 : x4-1];
                float qr = R[(tx==31) ? 131 : x4+4];
                sx  += ql  + q.x + q.y;
                sy  += q.x + q.y + q.z;
                szz += q.y + q.z + q.w;
                sw  += q.z + q.w + qr;
            }
            const float inv9 = 1.f/9.f;
            over = val.x*(1.f - sx*inv9) + val.y*(1.f - sy*inv9)
                 + val.z*(1.f - szz*inv9) + val.w*(1.f - sw*inv9);
        }

        #pragma unroll
        for (int o = 32; o; o >>= 1) {
            occ  += __shfl_down(occ,  o, 64);
            surf += __shfl_down(surf, o, 64);
            over += __shfl_down(over, o, 64);
        }
        int lane = tid & 63, wid = tid >> 6;
        if (lane == 0) { sred[wid]=occ; sred[4+wid]=surf; sred[8+wid]=over; }
        __syncthreads();
        if (tid == 0) {
            p_occ [rid] = sred[0]+sred[1]+sred[2]+sred[3];
            p_surf[rid] = sred[4]+sred[5]+sred[6]+sred[7];
            p_over[rid] = sred[8]+sred[9]+sred[10]+sred[11];
        }
        #undef ROWS
    }
}

// ---------------------------------------------------------------------------
// finalize: sum partials (f64), combine with trap deltas.
// trap_sum = a_lo*(N - sum(v)) + sum(box deltas)
// ---------------------------------------------------------------------------
__global__ __launch_bounds__(1024) void finalize_k(
    const float* __restrict__ p_occ, const float* __restrict__ p_surf,
    const float* __restrict__ p_over, const float* __restrict__ p_trap,
    float* __restrict__ out)
{
    double occ=0, surf=0, over=0;
    for (int i = threadIdx.x; i < NBLK; i += 1024) {
        occ += p_occ[i]; surf += p_surf[i]; over += p_over[i];
    }
    __shared__ double sm[3][16];
    #pragma unroll
    for (int o = 32; o; o >>= 1) {
        occ  += __shfl_down(occ,  o, 64);
        surf += __shfl_down(surf, o, 64);
        over += __shfl_down(over, o, 64);
    }
    int lane = threadIdx.x & 63, wid = threadIdx.x >> 6;
    if (lane == 0) { sm[0][wid]=occ; sm[1][wid]=surf; sm[2][wid]=over; }
    __syncthreads();
    if (threadIdx.x == 0) {
        double so=0, ss=0, sv=0;
        for (int w = 0; w < 16; ++w) { so+=sm[0][w]; ss+=sm[1][w]; sv+=sm[2][w]; }
        double dS = (double)p_trap[0] + p_trap[1] + p_trap[2] + p_trap[3];
        double a_lo = 1.0 / (1.0 + exp(10.0));
        double N = (double)NTOT;
        double trap_sum = a_lo * (N - so) + dS;
        double occupancy = so / N;
        double occ_pen = 10.0 * (occupancy - 0.5) * (occupancy - 0.5);
        out[0] = (float)(sv / N);
        out[1] = (float)(ss / 27.0 / N - 100.0 * trap_sum / N - occ_pen);
    }
}

extern "C" void kernel_launch(void* const* d_in, const int* in_sizes, int n_in,
                              void* d_out, int out_size, void* d_ws, size_t ws_size,
                              hipStream_t stream)
{
    const float* v = (const float*)d_in[0];
    float* out = (float*)d_out;
    float* ws = (float*)d_ws;

    float* p_occ  = ws;
    float* p_surf = p_occ  + NBLK;
    float* p_over = p_surf + NBLK;
    float* p_trap = p_over + NBLK;   // 4 floats

    mega_k<<<NBLK + 4, 256, 0, stream>>>(v, p_occ, p_surf, p_over, p_trap);
    finalize_k<<<1, 1024, 0, stream>>>(p_occ, p_surf, p_over, p_trap, out);
}

// Round 11
// 84.487 us; speedup vs baseline: 1.1899x; 1.0561x over previous
//
#include <hip/hip_runtime.h>

#define HW    (128*128)
#define DHW   (128*128*128)
#define NTOT  (4*DHW)
#define NBLK  2048         // reduce blocks: 4 batches * 16 y-tiles * 32 z-chunks(4z)

__device__ __forceinline__ float sigf(float x){ return 1.0f/(1.0f+__expf(-x)); }
__device__ __forceinline__ float4 ld4(const float* p){ return *(const float4*)p; }

// ws float layout: p_occ[NBLK], p_surf[NBLK], p_over[NBLK], p_trap[4]

// ---------------------------------------------------------------------------
// mega_k: heterogeneous grid of 4+NBLK blocks.
//   blocks 0..3   : resin-trap 16^3 box sim (one per batch), hidden under reduce.
//   blocks 4..    : occ/surface/overhang reduction, 4 z-slices per block.
// Reduce path: P(y,x) = x-windowed 3-sum of the below plane, built at staging
// time (shuffles, no scalar LDS edge reads); 3x3 gather = 3 ds_read_b128 +
// 2 float4 adds. P for the next slice is rebuilt from the val registers of
// the current slice (2 halo rows from global); double-buffered P planes,
// one barrier per slice. Shfl-reduction paid once per 16 elements.
// ---------------------------------------------------------------------------
__global__ __launch_bounds__(256, 4) void mega_k(
    const float* __restrict__ v, float* __restrict__ p_occ,
    float* __restrict__ p_surf, float* __restrict__ p_over,
    float* __restrict__ p_trap)
{
    __shared__ float4 smem4[1445];          // 5780 floats (trap needs all of it)
    __shared__ float sred[16];
    float* smem = (float*)smem4;

    const int bid = blockIdx.x;
    const int tid = threadIdx.x;
    const float4 zero4 = make_float4(0,0,0,0);

    if (bid < 4) {
        // ================= trap box path (unchanged from R10, passed) ======
        const int b = bid;
        const size_t gb = (size_t)b * DHW;
        const int ty = tid & 15, tz = tid >> 4;
        const float a_lo = sigf(-10.0f), a_hi = sigf(10.0f);
        #define M(zz,yy) (smem + (((zz)*17 + (yy))*20))

        float m[16], nv[16];
        {
            const float* rv = v + gb + ((size_t)tz*128 + ty)*128;
            int dzy = abs(tz-5) + abs(ty-5);
            #pragma unroll
            for (int q = 0; q < 4; ++q) {
                int x4 = 4*q;
                float4 a = ld4(rv + x4);
                nv[x4+0]=1.f-a.x; nv[x4+1]=1.f-a.y; nv[x4+2]=1.f-a.z; nv[x4+3]=1.f-a.w;
                int d0=dzy+abs(x4+0-5), d1=dzy+abs(x4+1-5);
                int d2=dzy+abs(x4+2-5), d3=dzy+abs(x4+3-5);
                m[x4+0] = ((d0==0)?1.f:((d0==1)?a_hi:a_lo)) * nv[x4+0];
                m[x4+1] = ((d1==0)?1.f:((d1==1)?a_hi:a_lo)) * nv[x4+1];
                m[x4+2] = ((d2==0)?1.f:((d2==1)?a_hi:a_lo)) * nv[x4+2];
                m[x4+3] = ((d3==0)?1.f:((d3==1)?a_hi:a_lo)) * nv[x4+3];
                *(float4*)(M(tz,ty) + x4) = make_float4(m[x4+0],m[x4+1],m[x4+2],m[x4+3]);
            }
        }
        const float xrE = a_lo * (1.f - v[gb + ((size_t)tz*128 + ty)*128 + 16]);
        {
            int a = tid >> 4, e = tid & 15;
            M(16,a)[e] = a_lo * (1.f - v[gb + ((size_t)16*128 + a)*128 + e]);
            M(a,16)[e] = a_lo * (1.f - v[gb + ((size_t)a*128 + 16)*128 + e]);
        }
        __syncthreads();

        for (int it = 0; it < 9; ++it) {
            const float* YM = M(tz,ty-1);
            const float* YP = M(tz,ty+1);
            const float* ZM = M(tz-1,ty);
            const float* ZP = M(tz+1,ty);
            float nm[16];
            #pragma unroll
            for (int q = 0; q < 4; ++q) {
                int x4 = 4*q;
                float4 ym = (ty > 0) ? *(const float4*)(YM + x4) : zero4;
                float4 yp = *(const float4*)(YP + x4);
                float4 zm = (tz > 0) ? *(const float4*)(ZM + x4) : zero4;
                float4 zp = *(const float4*)(ZP + x4);
                float xl = (q == 0) ? 0.f : m[x4-1];
                float xr = (q == 3) ? xrE : m[x4+4];
                float s0 = xl      + m[x4+1] + ym.x + yp.x + zm.x + zp.x;
                float s1 = m[x4+0] + m[x4+2] + ym.y + yp.y + zm.y + zp.y;
                float s2 = m[x4+1] + m[x4+3] + ym.z + yp.z + zm.z + zp.z;
                float s3 = m[x4+2] + xr      + ym.w + yp.w + zm.w + zp.w;
                nm[x4+0] = fmaxf(m[x4+0], sigf(20.f*s0 - 10.f)) * nv[x4+0];
                nm[x4+1] = fmaxf(m[x4+1], sigf(20.f*s1 - 10.f)) * nv[x4+1];
                nm[x4+2] = fmaxf(m[x4+2], sigf(20.f*s2 - 10.f)) * nv[x4+2];
                nm[x4+3] = fmaxf(m[x4+3], sigf(20.f*s3 - 10.f)) * nv[x4+3];
            }
            __syncthreads();
            float* W = M(tz,ty);
            #pragma unroll
            for (int q = 0; q < 4; ++q) {
                int x4 = 4*q;
                *(float4*)(W + x4) = make_float4(nm[x4+0],nm[x4+1],nm[x4+2],nm[x4+3]);
                m[x4+0]=nm[x4+0]; m[x4+1]=nm[x4+1]; m[x4+2]=nm[x4+2]; m[x4+3]=nm[x4+3];
            }
            __syncthreads();
        }

        float d = 0.f;
        #pragma unroll
        for (int x = 0; x < 16; ++x) d += m[x] - a_lo * nv[x];
        #pragma unroll
        for (int o = 32; o; o >>= 1) d += __shfl_down(d, o, 64);
        int lane = tid & 63, wid = tid >> 6;
        if (lane == 0) sred[wid] = d;
        __syncthreads();
        if (tid == 0) p_trap[b] = sred[0] + sred[1] + sred[2] + sred[3];
        #undef M
    } else {
        // ================= reduce path =================
        const int rid = bid - 4;                 // 0..2047
        const int b   = rid >> 9;                // batch
        const int rem = rid & 511;
        const int z0  = (rem >> 4) * 4;          // z-chunk of 4
        const int y0  = (rem & 15) * 8;          // y-tile of 8
        const int tx  = tid & 31, ty = tid >> 5;
        const int x4  = tx * 4;
        const int y   = y0 + ty;
        const size_t gb = (size_t)b * DHW;
        #define PB(p,r) (smem + ((p)*1320 + (r)*132))

        float occ = 0.f, surf = 0.f, over = 0.f;

        // stage P of plane z0-1 (rows y0-1..y0+8)
        if (z0 >= 1) {
            const float* bp = v + gb + (size_t)(z0-1)*HW;
            for (int i = tid; i < 320; i += 256) {
                int r = i >> 5, xq = i & 31, xi = xq*4;
                int gy = y0 - 1 + r;
                float4 q = ((unsigned)gy <= 127u) ? ld4(bp + gy*128 + xi) : zero4;
                float ql = __shfl_up(q.w, 1);   if (xq == 0)  ql = 0.f;
                float qr = __shfl_down(q.x, 1); if (xq == 31) qr = 0.f;
                *(float4*)(PB(0,r) + xi) =
                    make_float4(ql+q.x+q.y, q.x+q.y+q.z, q.y+q.z+q.w, q.z+q.w+qr);
            }
        }
        __syncthreads();

        const float wy = (y==0 || y==127) ? 2.f : 3.f;
        const float wx0 = (x4==0)   ? 2.f : 3.f;
        const float wx3 = (x4==124) ? 2.f : 3.f;
        const float inv9 = 1.f/9.f;

        int pb = 0;
        for (int s = 0; s < 4; ++s) {
            const int z = z0 + s;
            const float* cp = v + gb + (size_t)z*HW;
            float4 val = ld4(cp + y*128 + x4);

            occ += val.x + val.y + val.z + val.w;
            float wz = (z==0 || z==127) ? 2.f : 3.f;
            surf += wz*wy*(wx0*val.x + 3.f*val.y + 3.f*val.z + wx3*val.w);

            if (z >= 1) {
                float4 a = *(const float4*)(PB(pb, ty)   + x4);
                float4 c = *(const float4*)(PB(pb, ty+1) + x4);
                float4 d = *(const float4*)(PB(pb, ty+2) + x4);
                float4 S = make_float4(a.x+c.x+d.x, a.y+c.y+d.y,
                                       a.z+c.z+d.z, a.w+c.w+d.w);
                over += val.x*(1.f - S.x*inv9) + val.y*(1.f - S.y*inv9)
                      + val.z*(1.f - S.z*inv9) + val.w*(1.f - S.w*inv9);
            }

            if (s < 3) {
                // build P of plane z (below of z+1) into the other buffer
                float ql = __shfl_up(val.w, 1);   if (tx == 0)  ql = 0.f;
                float qr = __shfl_down(val.x, 1); if (tx == 31) qr = 0.f;
                *(float4*)(PB(pb^1, ty+1) + x4) =
                    make_float4(ql+val.x+val.y, val.x+val.y+val.z,
                                val.y+val.z+val.w, val.z+val.w+qr);
                if (tid < 64) {   // halo rows y0-1 (r=0) and y0+8 (r=9)
                    int h = tid >> 5, xq = tid & 31, xi = xq*4;
                    int gy = h ? (y0 + 8) : (y0 - 1);
                    float4 q = ((unsigned)gy <= 127u) ? ld4(cp + gy*128 + xi) : zero4;
                    float hl = __shfl_up(q.w, 1);   if (xq == 0)  hl = 0.f;
                    float hr = __shfl_down(q.x, 1); if (xq == 31) hr = 0.f;
                    *(float4*)(PB(pb^1, h*9) + xi) =
                        make_float4(hl+q.x+q.y, q.x+q.y+q.z, q.y+q.z+q.w, q.z+q.w+hr);
                }
                pb ^= 1;
            }
            __syncthreads();
        }

        #pragma unroll
        for (int o = 32; o; o >>= 1) {
            occ  += __shfl_down(occ,  o, 64);
            surf += __shfl_down(surf, o, 64);
            over += __shfl_down(over, o, 64);
        }
        int lane = tid & 63, wid = tid >> 6;
        if (lane == 0) { sred[wid]=occ; sred[4+wid]=surf; sred[8+wid]=over; }
        __syncthreads();
        if (tid == 0) {
            p_occ [rid] = sred[0]+sred[1]+sred[2]+sred[3];
            p_surf[rid] = sred[4]+sred[5]+sred[6]+sred[7];
            p_over[rid] = sred[8]+sred[9]+sred[10]+sred[11];
        }
        #undef PB
    }
}

// ---------------------------------------------------------------------------
// finalize: sum partials (f64), combine with trap deltas.
// trap_sum = a_lo*(N - sum(v)) + sum(box deltas)
// ---------------------------------------------------------------------------
__global__ __launch_bounds__(1024) void finalize_k(
    const float* __restrict__ p_occ, const float* __restrict__ p_surf,
    const float* __restrict__ p_over, const float* __restrict__ p_trap,
    float* __restrict__ out)
{
    double occ=0, surf=0, over=0;
    for (int i = threadIdx.x; i < NBLK; i += 1024) {
        occ += p_occ[i]; surf += p_surf[i]; over += p_over[i];
    }
    __shared__ double sm[3][16];
    #pragma unroll
    for (int o = 32; o; o >>= 1) {
        occ  += __shfl_down(occ,  o, 64);
        surf += __shfl_down(surf, o, 64);
        over += __shfl_down(over, o, 64);
    }
    int lane = threadIdx.x & 63, wid = threadIdx.x >> 6;
    if (lane == 0) { sm[0][wid]=occ; sm[1][wid]=surf; sm[2][wid]=over; }
    __syncthreads();
    if (threadIdx.x == 0) {
        double so=0, ss=0, sv=0;
        for (int w = 0; w < 16; ++w) { so+=sm[0][w]; ss+=sm[1][w]; sv+=sm[2][w]; }
        double dS = (double)p_trap[0] + p_trap[1] + p_trap[2] + p_trap[3];
        double a_lo = 1.0 / (1.0 + exp(10.0));
        double N = (double)NTOT;
        double trap_sum = a_lo * (N - so) + dS;
        double occupancy = so / N;
        double occ_pen = 10.0 * (occupancy - 0.5) * (occupancy - 0.5);
        out[0] = (float)(sv / N);
        out[1] = (float)(ss / 27.0 / N - 100.0 * trap_sum / N - occ_pen);
    }
}

extern "C" void kernel_launch(void* const* d_in, const int* in_sizes, int n_in,
                              void* d_out, int out_size, void* d_ws, size_t ws_size,
                              hipStream_t stream)
{
    const float* v = (const float*)d_in[0];
    float* out = (float*)d_out;
    float* ws = (float*)d_ws;

    float* p_occ  = ws;
    float* p_surf = p_occ  + NBLK;
    float* p_over = p_surf + NBLK;
    float* p_trap = p_over + NBLK;   // 4 floats

    mega_k<<<NBLK + 4, 256, 0, stream>>>(v, p_occ, p_surf, p_over, p_trap);
    finalize_k<<<1, 1024, 0, stream>>>(p_occ, p_surf, p_over, p_trap, out);
}